// Round 2
// baseline (202.187 us; speedup 1.0000x reference)
//
#include <hip/hip_runtime.h>
#include <float.h>
#include <math.h>

#define DIM    1024
#define NROWS  131072
#define TOPK   32
#define TAU    0.2f
#define CHUNK  512
#define NCHUNK (NROWS / CHUNK)   // 256
#define NCAND  (NCHUNK * TOPK)   // 8192

// ---------------------------------------------------------------------------
// Kernel 1: logits[row] = dot(K[row], query)   (RAW dot, scale applied later;
// scale>0 so top-k order is unaffected). Also zeroes full_attn[row].
//
// Layout: one wave computes 4 rows; 16 lanes per row (rsel = lane>>4,
// sub = lane&15). Each load instruction reads 4 x 256B contiguous segments
// (coalesced); the cross-lane reduce is 4 shfl steps SHARED by all 4 rows
// (vs 6 steps per row before). q staged in LDS (2-way bank aliasing = free).
// ---------------------------------------------------------------------------
__global__ __launch_bounds__(256) void logits_kernel(const float* __restrict__ Km,
                                                     const float* __restrict__ q,
                                                     float* __restrict__ logits,
                                                     float* __restrict__ full_attn) {
    __shared__ float q_s[DIM];
    const int t = threadIdx.x;
    *reinterpret_cast<float4*>(q_s + t * 4) =
        *reinterpret_cast<const float4*>(q + t * 4);
    __syncthreads();

    const int lane = t & 63;
    const int wave = t >> 6;
    const int sub  = lane & 15;   // column-position within the row group
    const int rsel = lane >> 4;   // which of the wave's 4 rows
    const int row  = (blockIdx.x * 4 + wave) * 4 + rsel;

    const float* kr = Km + (size_t)row * DIM;
    float acc = 0.f;
    #pragma unroll
    for (int c = 0; c < 16; ++c) {
        const int fo = c * 64 + sub * 4;
        float4 kv = *reinterpret_cast<const float4*>(kr + fo);
        float4 qv = *reinterpret_cast<const float4*>(q_s + fo);
        acc = fmaf(kv.x, qv.x, acc);
        acc = fmaf(kv.y, qv.y, acc);
        acc = fmaf(kv.z, qv.z, acc);
        acc = fmaf(kv.w, qv.w, acc);
    }
    // reduce over the 16 lanes of each row group (xor stays within group)
    #pragma unroll
    for (int off = 1; off < 16; off <<= 1) acc += __shfl_xor(acc, off, 64);

    if (sub == 0) {
        logits[row]    = acc;   // raw dot
        full_attn[row] = 0.f;   // final kernel scatters the 32 nonzeros
    }
}

// ---------------------------------------------------------------------------
// Kernel 2: per-block (1 wave) local top-32 of a 512-element chunk.
// 256 blocks -> 8192 (val, idx) candidates; global top-32 is a subset.
// ---------------------------------------------------------------------------
__global__ __launch_bounds__(64) void topk_local_kernel(const float* __restrict__ logits,
                                                        float* __restrict__ cand_val,
                                                        int* __restrict__ cand_idx) {
    const int lane = threadIdx.x;
    const int base = blockIdx.x * CHUNK;

    float v[8]; int gi[8];
    float4 a = *reinterpret_cast<const float4*>(logits + base + lane * 4);
    float4 b = *reinterpret_cast<const float4*>(logits + base + 256 + lane * 4);
    v[0] = a.x; v[1] = a.y; v[2] = a.z; v[3] = a.w;
    v[4] = b.x; v[5] = b.y; v[6] = b.z; v[7] = b.w;
    #pragma unroll
    for (int j = 0; j < 4; ++j) gi[j] = base + lane * 4 + j;
    #pragma unroll
    for (int j = 0; j < 4; ++j) gi[4 + j] = base + 256 + lane * 4 + j;

    for (int r = 0; r < TOPK; ++r) {
        float m = v[0]; int mi = gi[0];
        #pragma unroll
        for (int j = 1; j < 8; ++j)
            if (v[j] > m || (v[j] == m && gi[j] < mi)) { m = v[j]; mi = gi[j]; }
        #pragma unroll
        for (int off = 32; off > 0; off >>= 1) {
            float ov = __shfl_xor(m, off, 64);
            int   oi = __shfl_xor(mi, off, 64);
            if (ov > m || (ov == m && oi < mi)) { m = ov; mi = oi; }
        }
        #pragma unroll
        for (int j = 0; j < 8; ++j)
            if (gi[j] == mi) v[j] = -FLT_MAX;   // only the owner matches
        if (lane == 0) {
            cand_val[blockIdx.x * TOPK + r] = m;
            cand_idx[blockIdx.x * TOPK + r] = mi;
        }
    }
}

// ---------------------------------------------------------------------------
// Kernel 3 (1 block, 256 threads): computes scale = 1/(max(||q||,1e-12)*TAU),
// global top-32 of 8192 candidates (incremental per-thread running max),
// softmax of the scaled values, scatter into full_attn, out = attn @ V[idxs].
// ---------------------------------------------------------------------------
__global__ __launch_bounds__(256) void final_kernel(const float* __restrict__ cand_val,
                                                    const int* __restrict__ cand_idx,
                                                    const float* __restrict__ q,
                                                    const float* __restrict__ Vm,
                                                    float* __restrict__ out,
                                                    float* __restrict__ full_attn) {
    const int t = threadIdx.x;
    const int lane = t & 63, wave = t >> 6;
    __shared__ float wred_v[4];
    __shared__ int   wred_i[4];
    __shared__ float tval[TOPK];
    __shared__ int   tidx[TOPK];
    __shared__ float attn_s[TOPK];
    __shared__ float red4[4];
    __shared__ float scale_s;

    // ---- scale = 1 / (max(||q||,1e-12) * TAU) ----
    float ss = 0.f;
    for (int i = t; i < DIM; i += 256) { float vq = q[i]; ss = fmaf(vq, vq, ss); }
    #pragma unroll
    for (int off = 32; off > 0; off >>= 1) ss += __shfl_xor(ss, off, 64);
    if (lane == 0) red4[wave] = ss;
    __syncthreads();
    if (t == 0) {
        float s = red4[0] + red4[1] + red4[2] + red4[3];
        scale_s = 1.0f / (fmaxf(sqrtf(s), 1e-12f) * TAU);
    }

    // ---- load candidates (coalesced), per-thread running max ----
    float v[32]; int gi[32];
    #pragma unroll
    for (int k = 0; k < 32; ++k) {
        int c = t + 256 * k;
        v[k]  = cand_val[c];
        gi[k] = cand_idx[c];
    }
    float m = v[0]; int mi = gi[0];
    #pragma unroll
    for (int k = 1; k < 32; ++k)
        if (v[k] > m || (v[k] == m && gi[k] < mi)) { m = v[k]; mi = gi[k]; }

    __syncthreads();   // scale_s published

    // ---- 32 rounds of global argmax; only the winner's thread rescans ----
    for (int r = 0; r < TOPK; ++r) {
        float wm = m; int wmi = mi;
        #pragma unroll
        for (int off = 32; off > 0; off >>= 1) {
            float ov = __shfl_xor(wm, off, 64);
            int   oi = __shfl_xor(wmi, off, 64);
            if (ov > wm || (ov == wm && oi < wmi)) { wm = ov; wmi = oi; }
        }
        if (lane == 0) { wred_v[wave] = wm; wred_i[wave] = wmi; }
        __syncthreads();
        float gm = wred_v[0]; int gmi = wred_i[0];
        #pragma unroll
        for (int w = 1; w < 4; ++w) {
            float ov = wred_v[w]; int oi = wred_i[w];
            if (ov > gm || (ov == gm && oi < gmi)) { gm = ov; gmi = oi; }
        }
        if (t == 0) { tval[r] = gm; tidx[r] = gmi; }
        if (mi == gmi) {              // candidate indices are unique: 1 owner
            #pragma unroll
            for (int k = 0; k < 32; ++k)
                if (gi[k] == gmi) v[k] = -FLT_MAX;
            m = v[0]; mi = gi[0];
            #pragma unroll
            for (int k = 1; k < 32; ++k)
                if (v[k] > m || (v[k] == m && gi[k] < mi)) { m = v[k]; mi = gi[k]; }
        }
        __syncthreads();   // protects wred_* reuse, publishes tval/tidx
    }

    // ---- softmax over scaled top values (tval[0] is the max; scale>0) ----
    const float scale = scale_s;
    float sum = 0.f;
    #pragma unroll
    for (int j = 0; j < TOPK; ++j) sum += expf((tval[j] - tval[0]) * scale);
    if (t < TOPK) attn_s[t] = expf((tval[t] - tval[0]) * scale) / sum;
    __syncthreads();

    if (t < TOPK) full_attn[tidx[t]] = attn_s[t];

    // ---- out[d] = sum_j attn[j] * V[idx[j]][d] (coalesced over d) ----
    for (int d = t; d < DIM; d += 256) {
        float acc = 0.f;
        #pragma unroll
        for (int j = 0; j < TOPK; ++j)
            acc = fmaf(attn_s[j], Vm[(size_t)tidx[j] * DIM + d], acc);
        out[d] = acc;
    }
}

// ---------------------------------------------------------------------------
extern "C" void kernel_launch(void* const* d_in, const int* in_sizes, int n_in,
                              void* d_out, int out_size, void* d_ws, size_t ws_size,
                              hipStream_t stream) {
    const float* q  = (const float*)d_in[0];
    const float* Km = (const float*)d_in[1];
    const float* Vm = (const float*)d_in[2];
    // d_in[3] = topk scalar (32) — fixed by problem setup.

    float* out       = (float*)d_out;       // [0 .. 1024)
    float* full_attn = out + DIM;           // [1024 .. 1024+131072)

    float* logits   = (float*)d_ws;                 // NROWS floats
    float* cand_val = logits + NROWS;               // NCAND floats
    int*   cand_idx = (int*)(cand_val + NCAND);     // NCAND ints

    logits_kernel<<<NROWS / 16, 256, 0, stream>>>(Km, q, logits, full_attn);
    topk_local_kernel<<<NCHUNK, 64, 0, stream>>>(logits, cand_val, cand_idx);
    final_kernel<<<1, 256, 0, stream>>>(cand_val, cand_idx, q, Vm, out, full_attn);
}